// Round 4
// baseline (696.341 us; speedup 1.0000x reference)
//
#include <hip/hip_runtime.h>

#define D 64
#define NB 512          // dst-range buckets
#define NPB 196         // nodes per bucket: ceil(100000/512)
#define ZSTRIDE 65      // LDS z row stride (dwords), odd -> bank spread
#define EPB 2048        // edges per partition block (8 per thread)

// ---------------------------------------------------------------------------
// Phase 1: per-node gate projections. One 64-lane wave per node.
// pack[v] = (s_dst[v] + gate_b, s_src[v], d[v], 0)
// ---------------------------------------------------------------------------
__global__ __launch_bounds__(256) void node_phase(
    const float* __restrict__ h,
    const float* __restrict__ deg,
    const float* __restrict__ gate_w,
    const float* __restrict__ gate_b,
    float4* __restrict__ pack,
    int n_nodes)
{
    int gtid = blockIdx.x * blockDim.x + threadIdx.x;
    int node = gtid >> 6;
    int lane = threadIdx.x & 63;
    if (node >= n_nodes) return;

    float hv = h[(size_t)node * D + lane];
    float pd = hv * gate_w[lane];
    float ps = hv * gate_w[D + lane];

    #pragma unroll
    for (int off = 32; off > 0; off >>= 1) {
        pd += __shfl_xor(pd, off);
        ps += __shfl_xor(ps, off);
    }

    if (lane == 0) {
        float4 v;
        v.x = pd + gate_b[0];
        v.y = ps;
        v.z = deg[node];
        v.w = 0.0f;
        pack[node] = v;
    }
}

// ---------------------------------------------------------------------------
// 512-bin bucket histogram (LDS-privatized)
// ---------------------------------------------------------------------------
__global__ __launch_bounds__(256) void bin_hist(
    const int* __restrict__ dst, int* __restrict__ bcount, int n_edges)
{
    __shared__ int cnt[NB];
    for (int i = threadIdx.x; i < NB; i += 256) cnt[i] = 0;
    __syncthreads();
    int stride = gridDim.x * 256;
    for (int e = blockIdx.x * 256 + threadIdx.x; e < n_edges; e += stride)
        atomicAdd(&cnt[(unsigned)dst[e] / NPB], 1);
    __syncthreads();
    for (int i = threadIdx.x; i < NB; i += 256) {
        int c = cnt[i];
        if (c) atomicAdd(&bcount[i], c);
    }
}

// ---------------------------------------------------------------------------
// Exclusive scan of 512 bucket counts -> bases[513], init gcursor
// ---------------------------------------------------------------------------
__global__ __launch_bounds__(NB) void scan_bases(
    const int* __restrict__ bcount, int* __restrict__ bases,
    int* __restrict__ gcursor, int n_edges)
{
    __shared__ int sm[NB];
    int v = bcount[threadIdx.x];
    int orig = v;
    sm[threadIdx.x] = v;
    __syncthreads();
    for (int off = 1; off < NB; off <<= 1) {
        int add = (threadIdx.x >= (unsigned)off) ? sm[threadIdx.x - off] : 0;
        __syncthreads();
        sm[threadIdx.x] += add;
        __syncthreads();
    }
    int excl = sm[threadIdx.x] - orig;
    bases[threadIdx.x]   = excl;
    gcursor[threadIdx.x] = excl;
    if (threadIdx.x == NB - 1) bases[NB] = n_edges;
}

// ---------------------------------------------------------------------------
// Radix partition: edges -> 512 dst-range buckets.
// Block-local LDS ranking + one global reservation per (block,bucket):
// writes are ~64B runs into 512 L2-resident frontiers (no line thrash).
// payload = (src | dstloc<<17, bitcast(w))  [src<2^17, dstloc<196]
// ---------------------------------------------------------------------------
__global__ __launch_bounds__(256) void partition_kernel(
    const int* __restrict__ src, const int* __restrict__ dst,
    const float4* __restrict__ pack, int* __restrict__ gcursor,
    uint2* __restrict__ pairs, int n_edges)
{
    __shared__ int cnt[NB];
    __shared__ int base[NB];
    for (int i = threadIdx.x; i < NB; i += 256) cnt[i] = 0;
    __syncthreads();

    int e0 = blockIdx.x * EPB;
    uint2 payload[8];
    unsigned short bk[8], rk[8];

    #pragma unroll
    for (int k = 0; k < 8; ++k) {
        int e = e0 + k * 256 + threadIdx.x;
        if (e < n_edges) {
            int s = src[e], t = dst[e];
            unsigned b  = (unsigned)t / NPB;       // compile-time magic-mul
            unsigned dl = (unsigned)t - b * NPB;
            float4 pt = pack[t];
            float4 ps = pack[s];
            float a = tanhf(pt.x + ps.y);          // gate_b folded into pt.x
            float w = pt.z * ps.z * a;
            payload[k] = make_uint2((unsigned)s | (dl << 17), __float_as_uint(w));
            bk[k] = (unsigned short)b;
            rk[k] = (unsigned short)atomicAdd(&cnt[b], 1);
        } else {
            bk[k] = 0xFFFF;
        }
    }
    __syncthreads();

    for (int i = threadIdx.x; i < NB; i += 256) {
        int c = cnt[i];
        base[i] = c ? atomicAdd(&gcursor[i], c) : 0;
    }
    __syncthreads();

    #pragma unroll
    for (int k = 0; k < 8; ++k)
        if (bk[k] != 0xFFFF)
            pairs[base[bk[k]] + rk[k]] = payload[k];
}

// ---------------------------------------------------------------------------
// Bucket aggregation: one block per bucket, z slice resident in LDS.
// 16 edge-slots x 16 feature-lanes; lane c handles dwords {c,c+16,c+32,c+48};
// LDS row stride 65 (odd) -> ds_add_f32 bank spread (~2-way, free).
// ---------------------------------------------------------------------------
__global__ __launch_bounds__(256) void bucket_aggregate(
    const float* __restrict__ h, const uint2* __restrict__ pairs,
    const int* __restrict__ bases, float* __restrict__ z, int n_nodes)
{
    __shared__ float zl[NPB * ZSTRIDE];   // 196*65*4 = 50,960 B -> 3 blocks/CU
    for (int i = threadIdx.x; i < NPB * ZSTRIDE; i += 256) zl[i] = 0.0f;
    __syncthreads();

    int b    = blockIdx.x;
    int ebeg = bases[b];
    int eend = bases[b + 1];
    int slot = threadIdx.x >> 4;     // 0..15
    int c    = threadIdx.x & 15;

    int i = ebeg + slot;
    // 2-edge unrolled main loop (double the loads in flight)
    while (i + 16 < eend) {
        uint2 p0 = pairs[i];
        uint2 p1 = pairs[i + 16];
        const float* hr0 = h + (size_t)(p0.x & 0x1FFFFu) * D;
        const float* hr1 = h + (size_t)(p1.x & 0x1FFFFu) * D;
        float w0 = __uint_as_float(p0.y);
        float w1 = __uint_as_float(p1.y);
        float* zr0 = zl + (p0.x >> 17) * ZSTRIDE;
        float* zr1 = zl + (p1.x >> 17) * ZSTRIDE;
        float hv0[4], hv1[4];
        #pragma unroll
        for (int j = 0; j < 4; ++j) hv0[j] = hr0[c + 16 * j];
        #pragma unroll
        for (int j = 0; j < 4; ++j) hv1[j] = hr1[c + 16 * j];
        #pragma unroll
        for (int j = 0; j < 4; ++j) unsafeAtomicAdd(&zr0[c + 16 * j], hv0[j] * w0);
        #pragma unroll
        for (int j = 0; j < 4; ++j) unsafeAtomicAdd(&zr1[c + 16 * j], hv1[j] * w1);
        i += 32;
    }
    if (i < eend) {
        uint2 p = pairs[i];
        const float* hr = h + (size_t)(p.x & 0x1FFFFu) * D;
        float w = __uint_as_float(p.y);
        float* zr = zl + (p.x >> 17) * ZSTRIDE;
        #pragma unroll
        for (int j = 0; j < 4; ++j)
            unsafeAtomicAdd(&zr[c + 16 * j], hr[c + 16 * j] * w);
    }
    __syncthreads();

    // coalesced writeout: 4 nodes per pass (tid/64 = node, tid%64 = dword)
    int lw = threadIdx.x >> 6;
    int d  = threadIdx.x & 63;
    int v0 = b * NPB;
    for (int n = lw; n < NPB; n += 4) {
        int v = v0 + n;
        if (v < n_nodes) z[(size_t)v * D + d] = zl[n * ZSTRIDE + d];
    }
}

// ---------------------------------------------------------------------------
// Fallback (ws too small): direct atomic aggregation.
// ---------------------------------------------------------------------------
__global__ __launch_bounds__(256) void edge_phase_atomic(
    const float4* __restrict__ h4,
    const int* __restrict__ src, const int* __restrict__ dst,
    const float4* __restrict__ pack, float* __restrict__ z, int n_edges)
{
    int gtid = blockIdx.x * blockDim.x + threadIdx.x;
    int e_id = gtid >> 4;
    int lane = threadIdx.x & 15;
    if (e_id >= n_edges) return;
    int s = src[e_id], t = dst[e_id];
    float4 pt = pack[t], ps = pack[s];
    float a = tanhf(pt.x + ps.y);
    float e = pt.z * ps.z * a;
    float4 hv = h4[(size_t)s * (D / 4) + lane];
    float* zp = z + (size_t)t * D + lane * 4;
    unsafeAtomicAdd(zp + 0, hv.x * e);
    unsafeAtomicAdd(zp + 1, hv.y * e);
    unsafeAtomicAdd(zp + 2, hv.z * e);
    unsafeAtomicAdd(zp + 3, hv.w * e);
}

extern "C" void kernel_launch(void* const* d_in, const int* in_sizes, int n_in,
                              void* d_out, int out_size, void* d_ws, size_t ws_size,
                              hipStream_t stream)
{
    const float* h   = (const float*)d_in[0];
    const float* deg = (const float*)d_in[1];
    const float* gw  = (const float*)d_in[2];
    const float* gb  = (const float*)d_in[3];
    const int*   src = (const int*)d_in[4];
    const int*   dst = (const int*)d_in[5];

    int n_nodes = in_sizes[1];
    int n_edges = in_sizes[4];

    float* z = (float*)d_out;

    // --- workspace layout ---
    auto align = [](size_t x) { return (x + 255) & ~(size_t)255; };
    size_t pack_b  = align((size_t)n_nodes * sizeof(float4));
    size_t pairs_b = align((size_t)n_edges * sizeof(uint2));
    size_t bcnt_b  = align((size_t)NB * sizeof(int));
    size_t bases_b = align((size_t)(NB + 1) * sizeof(int));
    size_t gcur_b  = align((size_t)NB * sizeof(int));
    size_t need = pack_b + pairs_b + bcnt_b + bases_b + gcur_b;

    char* basep = (char*)d_ws;
    float4* pack    = (float4*)basep;  basep += pack_b;
    uint2*  pairs   = (uint2*)basep;   basep += pairs_b;
    int*    bcount  = (int*)basep;     basep += bcnt_b;
    int*    bases   = (int*)basep;     basep += bases_b;
    int*    gcursor = (int*)basep;

    // node phase (both paths need pack)
    {
        long long threads = (long long)n_nodes * 64;
        int blocks = (int)((threads + 255) / 256);
        node_phase<<<blocks, 256, 0, stream>>>(h, deg, gw, gb, pack, n_nodes);
    }

    if (ws_size < need || n_nodes > NB * NPB) {
        hipMemsetAsync(d_out, 0, (size_t)n_nodes * D * sizeof(float), stream);
        long long threads = (long long)n_edges * 16;
        int blocks = (int)((threads + 255) / 256);
        edge_phase_atomic<<<blocks, 256, 0, stream>>>((const float4*)h, src, dst, pack, z, n_edges);
        return;
    }

    hipMemsetAsync(bcount, 0, (size_t)NB * sizeof(int), stream);
    bin_hist<<<1024, 256, 0, stream>>>(dst, bcount, n_edges);
    scan_bases<<<1, NB, 0, stream>>>(bcount, bases, gcursor, n_edges);
    {
        int blocks = (n_edges + EPB - 1) / EPB;
        partition_kernel<<<blocks, 256, 0, stream>>>(src, dst, pack, gcursor, pairs, n_edges);
    }
    bucket_aggregate<<<NB, 256, 0, stream>>>(h, pairs, bases, z, n_nodes);
}

// Round 5
// 246.682 us; speedup vs baseline: 2.8228x; 2.8228x over previous
//
#include <hip/hip_runtime.h>

#define D 64
#define NB 512          // dst-range buckets
#define NPB 196         // nodes per bucket: ceil(100000/512)
#define EPB 2048        // edges per partition block (8 per thread)

// ---------------------------------------------------------------------------
// Phase 1: per-node gate projections. One 64-lane wave per node.
// pack[v] = (s_dst[v] + gate_b, s_src[v], d[v], 0)
// ---------------------------------------------------------------------------
__global__ __launch_bounds__(256) void node_phase(
    const float* __restrict__ h,
    const float* __restrict__ deg,
    const float* __restrict__ gate_w,
    const float* __restrict__ gate_b,
    float4* __restrict__ pack,
    int n_nodes)
{
    int gtid = blockIdx.x * blockDim.x + threadIdx.x;
    int node = gtid >> 6;
    int lane = threadIdx.x & 63;
    if (node >= n_nodes) return;

    float hv = h[(size_t)node * D + lane];
    float pd = hv * gate_w[lane];
    float ps = hv * gate_w[D + lane];

    #pragma unroll
    for (int off = 32; off > 0; off >>= 1) {
        pd += __shfl_xor(pd, off);
        ps += __shfl_xor(ps, off);
    }

    if (lane == 0) {
        float4 v;
        v.x = pd + gate_b[0];
        v.y = ps;
        v.z = deg[node];
        v.w = 0.0f;
        pack[node] = v;
    }
}

// ---------------------------------------------------------------------------
// 512-bin bucket histogram (LDS-privatized)
// ---------------------------------------------------------------------------
__global__ __launch_bounds__(256) void bin_hist(
    const int* __restrict__ dst, int* __restrict__ bcount, int n_edges)
{
    __shared__ int cnt[NB];
    for (int i = threadIdx.x; i < NB; i += 256) cnt[i] = 0;
    __syncthreads();
    int stride = gridDim.x * 256;
    for (int e = blockIdx.x * 256 + threadIdx.x; e < n_edges; e += stride)
        atomicAdd(&cnt[(unsigned)dst[e] / NPB], 1);
    __syncthreads();
    for (int i = threadIdx.x; i < NB; i += 256) {
        int c = cnt[i];
        if (c) atomicAdd(&bcount[i], c);
    }
}

// ---------------------------------------------------------------------------
// Exclusive scan of 512 bucket counts -> bases[513], init gcursor
// ---------------------------------------------------------------------------
__global__ __launch_bounds__(NB) void scan_bases(
    const int* __restrict__ bcount, int* __restrict__ bases,
    int* __restrict__ gcursor, int n_edges)
{
    __shared__ int sm[NB];
    int v = bcount[threadIdx.x];
    int orig = v;
    sm[threadIdx.x] = v;
    __syncthreads();
    for (int off = 1; off < NB; off <<= 1) {
        int add = (threadIdx.x >= (unsigned)off) ? sm[threadIdx.x - off] : 0;
        __syncthreads();
        sm[threadIdx.x] += add;
        __syncthreads();
    }
    int excl = sm[threadIdx.x] - orig;
    bases[threadIdx.x]   = excl;
    gcursor[threadIdx.x] = excl;
    if (threadIdx.x == NB - 1) bases[NB] = n_edges;
}

// ---------------------------------------------------------------------------
// Radix partition: edges -> 512 dst-range buckets (pairs1, bucket-grouped).
// Block-local LDS ranking + one global reservation per (block,bucket):
// writes are ~64B runs into 512 L2-resident frontiers.
// payload = (src | dstloc<<17, bitcast(w))  [src<2^17, dstloc<196]
// ---------------------------------------------------------------------------
__global__ __launch_bounds__(256) void partition_kernel(
    const int* __restrict__ src, const int* __restrict__ dst,
    const float4* __restrict__ pack, int* __restrict__ gcursor,
    uint2* __restrict__ pairs1, int n_edges)
{
    __shared__ int cnt[NB];
    __shared__ int base[NB];
    for (int i = threadIdx.x; i < NB; i += 256) cnt[i] = 0;
    __syncthreads();

    int e0 = blockIdx.x * EPB;
    uint2 payload[8];
    unsigned short bk[8], rk[8];

    #pragma unroll
    for (int k = 0; k < 8; ++k) {
        int e = e0 + k * 256 + threadIdx.x;
        if (e < n_edges) {
            int s = src[e], t = dst[e];
            unsigned b  = (unsigned)t / NPB;       // compile-time magic-mul
            unsigned dl = (unsigned)t - b * NPB;
            float4 pt = pack[t];
            float4 ps = pack[s];
            float a = tanhf(pt.x + ps.y);          // gate_b folded into pt.x
            float w = pt.z * ps.z * a;
            payload[k] = make_uint2((unsigned)s | (dl << 17), __float_as_uint(w));
            bk[k] = (unsigned short)b;
            rk[k] = (unsigned short)atomicAdd(&cnt[b], 1);
        } else {
            bk[k] = 0xFFFF;
        }
    }
    __syncthreads();

    for (int i = threadIdx.x; i < NB; i += 256) {
        int c = cnt[i];
        base[i] = c ? atomicAdd(&gcursor[i], c) : 0;
    }
    __syncthreads();

    #pragma unroll
    for (int k = 0; k < 8; ++k)
        if (bk[k] != 0xFFFF)
            pairs1[base[bk[k]] + rk[k]] = payload[k];
}

// ---------------------------------------------------------------------------
// Per-bucket counting sort -> exact CSR. One block per bucket.
// Scatter window = bucket range (~25 KB) -> stays L2-hot, no line thrash.
// pairs2[pos] = (src, w); offsets[v] global CSR row starts.
// ---------------------------------------------------------------------------
__global__ __launch_bounds__(256) void bucket_csr(
    const uint2* __restrict__ pairs1, const int* __restrict__ bases,
    int* __restrict__ offsets, uint2* __restrict__ pairs2,
    int n_nodes, int n_edges)
{
    __shared__ int cnt[NPB];
    __shared__ int cur[NPB];
    __shared__ int sm[256];

    int b = blockIdx.x;
    int ebeg = bases[b];
    int eend = bases[b + 1];

    for (int i = threadIdx.x; i < NPB; i += 256) cnt[i] = 0;
    __syncthreads();

    for (int i = ebeg + threadIdx.x; i < eend; i += 256)
        atomicAdd(&cnt[pairs1[i].x >> 17], 1);
    __syncthreads();

    // exclusive scan of the 196 counters (Hillis-Steele, padded to 256)
    int v = (threadIdx.x < NPB) ? cnt[threadIdx.x] : 0;
    int orig = v;
    sm[threadIdx.x] = v;
    __syncthreads();
    for (int off = 1; off < 256; off <<= 1) {
        int add = (threadIdx.x >= (unsigned)off) ? sm[threadIdx.x - off] : 0;
        __syncthreads();
        sm[threadIdx.x] += add;
        __syncthreads();
    }
    if (threadIdx.x < NPB) {
        int excl = sm[threadIdx.x] - orig;
        cur[threadIdx.x] = ebeg + excl;
        int vnode = b * NPB + threadIdx.x;
        if (vnode < n_nodes) offsets[vnode] = ebeg + excl;
    }
    if (b == 0 && threadIdx.x == 0) offsets[n_nodes] = n_edges;
    __syncthreads();

    for (int i = ebeg + threadIdx.x; i < eend; i += 256) {
        uint2 p = pairs1[i];
        int dl = p.x >> 17;
        int pos = atomicAdd(&cur[dl], 1);     // LDS int atomic (ds_add)
        pairs2[pos] = make_uint2(p.x & 0x1FFFFu, p.y);
    }
}

// ---------------------------------------------------------------------------
// Gather aggregation (round-3 proven): one 64-lane wave per node.
// lane = slot(2b)*16 + chunk(4b): 4 edges in flight x 16 float4 chunks.
// ---------------------------------------------------------------------------
__global__ __launch_bounds__(256) void aggregate_kernel(
    const float4* __restrict__ h4, const uint2* __restrict__ pairs,
    const int* __restrict__ offsets, float4* __restrict__ z4, int n_nodes)
{
    int gtid = blockIdx.x * blockDim.x + threadIdx.x;
    int node = gtid >> 6;
    if (node >= n_nodes) return;
    int lane  = threadIdx.x & 63;
    int slot  = lane >> 4;
    int chunk = lane & 15;

    int beg = offsets[node];
    int end = offsets[node + 1];

    float4 acc = make_float4(0.f, 0.f, 0.f, 0.f);
    for (int i = beg + slot; i < end; i += 4) {
        uint2 p = pairs[i];
        float w = __uint_as_float(p.y);
        float4 hv = h4[(size_t)p.x * (D / 4) + chunk];
        acc.x += hv.x * w;
        acc.y += hv.y * w;
        acc.z += hv.z * w;
        acc.w += hv.w * w;
    }

    #pragma unroll
    for (int off = 16; off <= 32; off <<= 1) {
        acc.x += __shfl_xor(acc.x, off);
        acc.y += __shfl_xor(acc.y, off);
        acc.z += __shfl_xor(acc.z, off);
        acc.w += __shfl_xor(acc.w, off);
    }

    if (slot == 0) z4[(size_t)node * (D / 4) + chunk] = acc;
}

// ---------------------------------------------------------------------------
// Fallback (ws too small): direct atomic aggregation.
// ---------------------------------------------------------------------------
__global__ __launch_bounds__(256) void edge_phase_atomic(
    const float4* __restrict__ h4,
    const int* __restrict__ src, const int* __restrict__ dst,
    const float4* __restrict__ pack, float* __restrict__ z, int n_edges)
{
    int gtid = blockIdx.x * blockDim.x + threadIdx.x;
    int e_id = gtid >> 4;
    int lane = threadIdx.x & 15;
    if (e_id >= n_edges) return;
    int s = src[e_id], t = dst[e_id];
    float4 pt = pack[t], ps = pack[s];
    float a = tanhf(pt.x + ps.y);
    float e = pt.z * ps.z * a;
    float4 hv = h4[(size_t)s * (D / 4) + lane];
    float* zp = z + (size_t)t * D + lane * 4;
    unsafeAtomicAdd(zp + 0, hv.x * e);
    unsafeAtomicAdd(zp + 1, hv.y * e);
    unsafeAtomicAdd(zp + 2, hv.z * e);
    unsafeAtomicAdd(zp + 3, hv.w * e);
}

extern "C" void kernel_launch(void* const* d_in, const int* in_sizes, int n_in,
                              void* d_out, int out_size, void* d_ws, size_t ws_size,
                              hipStream_t stream)
{
    const float* h   = (const float*)d_in[0];
    const float* deg = (const float*)d_in[1];
    const float* gw  = (const float*)d_in[2];
    const float* gb  = (const float*)d_in[3];
    const int*   src = (const int*)d_in[4];
    const int*   dst = (const int*)d_in[5];

    int n_nodes = in_sizes[1];
    int n_edges = in_sizes[4];

    float* z = (float*)d_out;

    // --- workspace layout ---
    auto align = [](size_t x) { return (x + 255) & ~(size_t)255; };
    size_t pack_b   = align((size_t)n_nodes * sizeof(float4));
    size_t pairs2_b = align((size_t)n_edges * sizeof(uint2));
    size_t offs_b   = align(((size_t)n_nodes + 1) * sizeof(int));
    size_t bcnt_b   = align((size_t)NB * sizeof(int));
    size_t bases_b  = align((size_t)(NB + 1) * sizeof(int));
    size_t gcur_b   = align((size_t)NB * sizeof(int));
    size_t need = pack_b + pairs2_b + offs_b + bcnt_b + bases_b + gcur_b;

    char* basep = (char*)d_ws;
    float4* pack    = (float4*)basep;  basep += pack_b;
    uint2*  pairs2  = (uint2*)basep;   basep += pairs2_b;
    int*    offsets = (int*)basep;     basep += offs_b;
    int*    bcount  = (int*)basep;     basep += bcnt_b;
    int*    bases   = (int*)basep;     basep += bases_b;
    int*    gcursor = (int*)basep;

    // pairs1 staged in d_out (z is fully overwritten by aggregate afterwards)
    uint2* pairs1 = (uint2*)d_out;
    bool out_fits_pairs = (size_t)out_size * sizeof(float) >= (size_t)n_edges * sizeof(uint2);

    // node phase (both paths need pack)
    {
        long long threads = (long long)n_nodes * 64;
        int blocks = (int)((threads + 255) / 256);
        node_phase<<<blocks, 256, 0, stream>>>(h, deg, gw, gb, pack, n_nodes);
    }

    if (ws_size < need || n_nodes > NB * NPB || !out_fits_pairs) {
        hipMemsetAsync(d_out, 0, (size_t)n_nodes * D * sizeof(float), stream);
        long long threads = (long long)n_edges * 16;
        int blocks = (int)((threads + 255) / 256);
        edge_phase_atomic<<<blocks, 256, 0, stream>>>((const float4*)h, src, dst, pack, z, n_edges);
        return;
    }

    hipMemsetAsync(bcount, 0, (size_t)NB * sizeof(int), stream);
    bin_hist<<<1024, 256, 0, stream>>>(dst, bcount, n_edges);
    scan_bases<<<1, NB, 0, stream>>>(bcount, bases, gcursor, n_edges);
    {
        int blocks = (n_edges + EPB - 1) / EPB;
        partition_kernel<<<blocks, 256, 0, stream>>>(src, dst, pack, gcursor, pairs1, n_edges);
    }
    bucket_csr<<<NB, 256, 0, stream>>>(pairs1, bases, offsets, pairs2, n_nodes, n_edges);
    {
        long long threads = (long long)n_nodes * 64;
        int blocks = (int)((threads + 255) / 256);
        aggregate_kernel<<<blocks, 256, 0, stream>>>((const float4*)h, pairs2, offsets, (float4*)z, n_nodes);
    }
}